// Round 4
// baseline (1772.566 us; speedup 1.0000x reference)
//
#include <hip/hip_runtime.h>

#define B_  512
#define T_  1024
#define F_  128
#define H_  81
#define G3  243
#define GPX 244                 // xg row stride (floats), layout [b][t][GPX]

typedef unsigned short u16;
typedef __attribute__((ext_vector_type(8))) short bf16x8;
typedef __attribute__((ext_vector_type(4))) float f32x4;
typedef __attribute__((ext_vector_type(2))) float f32x2;

__device__ __forceinline__ float bf2f(u16 u) {
    union { unsigned int i; float f; } v; v.i = ((unsigned int)u) << 16; return v.f;
}
__device__ __forceinline__ u16 f2bf(float f) {
    union { float f; unsigned int i; } v; v.f = f;
    unsigned int i = v.i;
    return (u16)((i + 0x7fffu + ((i >> 16) & 1u)) >> 16);
}
__device__ __forceinline__ float rcp_(float x) { return __builtin_amdgcn_rcpf(x); }
__device__ __forceinline__ float sigmoidf_(float x) { return rcp_(1.f + __expf(-x)); }
__device__ __forceinline__ float tanhf_(float x) {
    return fmaf(-2.f, rcp_(__expf(2.f * x) + 1.f), 1.f);
}
// barrier without vmcnt(0) drain: LDS-correct (lgkmcnt(0) before s_barrier),
// leaves global prefetch loads in flight (m139/AITER technique).
__device__ __forceinline__ void barrier_nodrain() {
    asm volatile("s_waitcnt lgkmcnt(0)\n\ts_barrier" ::: "memory");
}

// ---------------------------------------------------------------------------
// K0: split W_ih fp32 -> bf16 hi/lo.
// ---------------------------------------------------------------------------
__global__ void wsplit_kernel(const float* __restrict__ W,
                              u16* __restrict__ hi, u16* __restrict__ lo)
{
    const int i = blockIdx.x * 256 + threadIdx.x;
    if (i < G3 * F_) {
        const float v = W[i];
        const u16 h = f2bf(v);
        hi[i] = h;
        lo[i] = f2bf(v - bf2f(h));
    }
}

// ---------------------------------------------------------------------------
// K1: xg[b][t][g] = x[b][t]·W_ih[g] + b_ih[g]  (split-bf16 MFMA, 3 terms).
// ---------------------------------------------------------------------------
__global__ __launch_bounds__(256, 2) void xg_gemm(const float* __restrict__ x,
                                                  const u16* __restrict__ Whi,
                                                  const u16* __restrict__ Wlo,
                                                  const float* __restrict__ b_ih,
                                                  float* __restrict__ xg)
{
    __shared__ __align__(16) u16 ws_hi[G3][64];
    __shared__ __align__(16) u16 ws_lo[G3][64];

    const int tid  = threadIdx.x;
    const int wave = tid >> 6, lane = tid & 63;
    const int l15  = lane & 15, q = lane >> 4;
    const int b    = blockIdx.x & 511;
    const int t0   = (blockIdx.x >> 9) << 7;

    f32x4 acc[2][16];
#pragma unroll
    for (int mt = 0; mt < 2; ++mt)
#pragma unroll
        for (int gt = 0; gt < 16; ++gt) acc[mt][gt] = (f32x4){0.f, 0.f, 0.f, 0.f};

    for (int half = 0; half < 2; ++half) {
        if (half) __syncthreads();            // protect LDS reuse
#pragma unroll
        for (int it = 0; it < 16; ++it) {
            const int i = it * 256 + tid;
            if (i < 2 * G3 * 8) {
                const bool lo = (i >= G3 * 8);
                const int j = lo ? (i - G3 * 8) : i;
                const int g = j >> 3, c = j & 7;
                const uint4 v = *(const uint4*)((lo ? Wlo : Whi)
                                                + (size_t)g * F_ + half * 64 + c * 8);
                *(uint4*)&((lo ? ws_lo : ws_hi)[g][((c + g) & 7) * 8]) = v;
            }
        }
        __syncthreads();

#pragma unroll
        for (int kcl = 0; kcl < 2; ++kcl) {
            bf16x8 aHi[2], aLo[2];
#pragma unroll
            for (int mt = 0; mt < 2; ++mt) {
                const float* xr = x + ((size_t)b * T_ + t0 + (wave * 2 + mt) * 16 + l15) * F_
                                  + half * 64 + kcl * 32 + q * 8;
                float xv[8];
                *(float4*)&xv[0] = *(const float4*)(xr);
                *(float4*)&xv[4] = *(const float4*)(xr + 4);
#pragma unroll
                for (int j = 0; j < 8; ++j) {
                    const u16 h = f2bf(xv[j]);
                    aHi[mt][j] = (short)h;
                    aLo[mt][j] = (short)f2bf(xv[j] - bf2f(h));
                }
            }
#pragma unroll
            for (int gt = 0; gt < 16; ++gt) {
                const int gr  = gt * 16 + l15;
                const int grc = (gr < G3) ? gr : (G3 - 1);
                const int sl  = ((kcl * 4 + q + grc) & 7) * 8;
                const bf16x8 bHi = *(const bf16x8*)&ws_hi[grc][sl];
                const bf16x8 bLo = *(const bf16x8*)&ws_lo[grc][sl];
#pragma unroll
                for (int mt = 0; mt < 2; ++mt) {
                    acc[mt][gt] = __builtin_amdgcn_mfma_f32_16x16x32_bf16(aHi[mt], bHi, acc[mt][gt], 0, 0, 0);
                    acc[mt][gt] = __builtin_amdgcn_mfma_f32_16x16x32_bf16(aHi[mt], bLo, acc[mt][gt], 0, 0, 0);
                    acc[mt][gt] = __builtin_amdgcn_mfma_f32_16x16x32_bf16(aLo[mt], bHi, acc[mt][gt], 0, 0, 0);
                }
            }
        }
    }
#pragma unroll
    for (int gt = 0; gt < 16; ++gt) {
        const int g = gt * 16 + l15;
        if (g < G3) {
            const float bias = b_ih[g];
#pragma unroll
            for (int mt = 0; mt < 2; ++mt) {
                const int trow = t0 + (wave * 2 + mt) * 16 + q * 4;
#pragma unroll
                for (int c = 0; c < 4; ++c)
                    xg[((size_t)b * T_ + trow + c) * GPX + g] = acc[mt][gt][c] + bias;
            }
        }
    }
}

// ---------------------------------------------------------------------------
// K2: GRU recurrence, v5 — offset schedule + WAVE SPECIALIZATION.
//     v4 post-mortem: offset pipeline regressed (693->896) because GATE ran
//     on tid 0..80 == dot threads: "dot || gate" was really "dot ; gate"
//     serialized in-thread, and the barrier stretched every interval to that
//     serial chain. The wall is a LATENCY chain (h-read ~120cy -> fma ->
//     part-write/bar -> part-read ~120cy -> transcendental chain -> h-write/
//     bar), not LDS throughput.
//     v5: 512 threads (8 waves). Dot threads tid 0..242 (waves 0-3, same
//     weight layout, 84 resident VGPRs). Gate threads tid 256..336 (b0) and
//     384..464 (b1) on waves 4-7 — DISJOINT from dot waves, so the gate
//     chain truly executes under the other batch's dot.
//       interval A: DOT(b1,t) || GATE(b0,t)   -> barrier
//       interval B: DOT(b0,t+1) || GATE(b1,t) -> barrier
//     One barrier/interval; every LDS writer->reader pair (part, h_s, xn_s;
//     all per-batch buffers) is exactly one barrier apart. DOT/refill are
//     if(act)-guarded so gate waves issue no h-broadcast reads (would double
//     LDS return traffic). Math order per batch identical to v3 -> bitwise
//     same result. Dead last DOT (t==T-1 interval B) writes an unread part.
// ---------------------------------------------------------------------------
__global__ __launch_bounds__(512, 2) void gru_kernel(const float* __restrict__ xg,
                                                     const float* __restrict__ W_hh,
                                                     const float* __restrict__ b_hh,
                                                     float* __restrict__ h_out)
{
    __shared__ __align__(16) float h_s[2][88];       // h padded, 81..87 = 0
    __shared__ float part[2][3][244];                // [batch][p][row]
    __shared__ float xn_s[2][84];                    // n-gate x-terms

    const int tid = threadIdx.x;
    const int b0 = blockIdx.x * 2, b1 = b0 + 1;
    const bool act = tid < G3;                       // dot role (waves 0-3)
    const int p   = (tid >= 162) ? 2 : ((tid >= 81) ? 1 : 0);
    const int j   = act ? (tid - p * 81) : 0;        // hidden-unit index
    const int k0  = p * 28;                          // k-third base (padded H=84)

    // dot weights: rows {j, j+81, j+162}, k in [k0, k0+28); zero-padded
    f32x2 w2[3][14];
#pragma unroll
    for (int i = 0; i < 3; ++i) {
        const float* wr = W_hh + (size_t)(j + 81 * i) * H_ + k0;
#pragma unroll
        for (int c = 0; c < 14; ++c) {
            const float e0 = (act && (k0 + 2 * c)     < H_) ? wr[2 * c]     : 0.f;
            const float e1 = (act && (k0 + 2 * c + 1) < H_) ? wr[2 * c + 1] : 0.f;
            w2[i][c] = (f32x2){e0, e1};
        }
    }
#pragma unroll
    for (int i = 0; i < 3; ++i)
#pragma unroll
        for (int c = 0; c < 14; ++c)
            asm volatile("" : "+v"(w2[i][c]));       // pin in ArchVGPRs

    // gate roles on DEDICATED waves: b0 -> tid 256..336, b1 -> tid 384..464
    const int gq = (tid >= 256 && tid < 256 + H_) ? 0
                 : ((tid >= 384 && tid < 384 + H_) ? 1 : -1);
    const int gi = (gq == 0) ? (tid - 256) : ((gq == 1) ? (tid - 384) : 0);
    const float br = (gq >= 0) ? b_hh[gi]          : 0.f;
    const float bz = (gq >= 0) ? b_hh[H_ + gi]     : 0.f;
    const float bn = (gq >= 0) ? b_hh[2 * H_ + gi] : 0.f;
    float hreg = 0.f;

    if (tid < 176) ((float*)h_s)[tid] = 0.f;
    __syncthreads();

    const float* xp0 = xg + (size_t)b0 * T_ * GPX + (act ? tid : 0);
    const float* xp1 = xg + (size_t)b1 * T_ * GPX + (act ? tid : 0);
    float xf0[4], xf1[4];
    if (act) {
#pragma unroll
        for (int u = 0; u < 4; ++u) {
            xf0[u] = xp0[(size_t)u * GPX];
            xf1[u] = xp1[(size_t)u * GPX];
        }
    }

    // dot: 3 rows x 28 k for batch bb; writes part[bb] (+ xn for p==2)
    auto DOT = [&](int bb, float xv) {
        f32x2 aA0 = {0.f, 0.f}, aA1 = {0.f, 0.f}, aA2 = {0.f, 0.f};
        f32x2 aB0 = {0.f, 0.f}, aB1 = {0.f, 0.f}, aB2 = {0.f, 0.f};
#pragma unroll
        for (int c = 0; c < 7; ++c) {
            const float4 h4 = ((const float4*)h_s[bb])[p * 7 + c];
            const f32x2 lo = {h4.x, h4.y}, hi = {h4.z, h4.w};
            aA0 = __builtin_elementwise_fma(w2[0][2 * c],     lo, aA0);
            aB0 = __builtin_elementwise_fma(w2[0][2 * c + 1], hi, aB0);
            aA1 = __builtin_elementwise_fma(w2[1][2 * c],     lo, aA1);
            aB1 = __builtin_elementwise_fma(w2[1][2 * c + 1], hi, aB1);
            aA2 = __builtin_elementwise_fma(w2[2][2 * c],     lo, aA2);
            aB2 = __builtin_elementwise_fma(w2[2][2 * c + 1], hi, aB2);
        }
        const f32x2 t0 = aA0 + aB0, t1 = aA1 + aB1, t2 = aA2 + aB2;
        const float s0 = t0.x + t0.y + ((p == 0) ? xv : 0.f);
        const float s1 = t1.x + t1.y + ((p == 1) ? xv : 0.f);
        const float s2 = t2.x + t2.y;
        if (p == 2) xn_s[bb][j] = xv;
        part[bb][p][j]       = s0;
        part[bb][p][j + 81]  = s1;
        part[bb][p][j + 162] = s2;
    };
    // gate for batch bb (dedicated gate waves only)
    auto GATE = [&](int bb) {
        if (gq == bb) {
            const float prer = part[bb][0][gi]       + part[bb][1][gi]       + part[bb][2][gi]       + br;
            const float prez = part[bb][0][gi + 81]  + part[bb][1][gi + 81]  + part[bb][2][gi + 81]  + bz;
            const float hn   = part[bb][0][gi + 162] + part[bb][1][gi + 162] + part[bb][2][gi + 162] + bn;
            const float rr = sigmoidf_(prer);
            const float zz = sigmoidf_(prez);
            const float nn = tanhf_(fmaf(rr, hn, xn_s[bb][gi]));
            hreg = nn + zz * (hreg - nn);
            h_s[bb][gi] = hreg;
        }
    };

    // prologue: dot(b0, t=0)
    if (act) DOT(0, xf0[0]);
    barrier_nodrain();
    if (act) xf0[0] = xp0[(size_t)4 * GPX];      // refill slot 0 with x0[4]

    for (int t4 = 0; t4 < T_; t4 += 4) {
#pragma unroll
        for (int u = 0; u < 4; ++u) {
            const int t = t4 + u;
            // interval A: dot(b1,t) || gate(b0,t)
            if (act) DOT(1, xf1[u]);
            GATE(0);
            barrier_nodrain();
            if (act) {   // refill b1 slot u with x1[t+4]
                const int tn = (t + 4 < T_) ? (t + 4) : (T_ - 1);
                xf1[u] = xp1[(size_t)tn * GPX];
            }
            // interval B: dot(b0,t+1) || gate(b1,t)
            const int un = (u + 1) & 3;
            if (act) DOT(0, xf0[un]);   // at t==T-1: dead work (part unread)
            GATE(1);
            barrier_nodrain();
            if (act) {   // refill b0 slot un with x0[t+5]
                const int tn = (t + 5 < T_) ? (t + 5) : (T_ - 1);
                xf0[un] = xp0[(size_t)tn * GPX];
            }
        }
    }

    if (gq == 0)      h_out[(size_t)b0 * H_ + gi] = hreg;
    else if (gq == 1) h_out[(size_t)b1 * H_ + gi] = hreg;
}

// ---------------------------------------------------------------------------
// K3: head. One block, 512 threads (thread = batch row), fp32 throughout.
// ---------------------------------------------------------------------------
__device__ __forceinline__ float block_sum(float v, float* red, int tid) {
#pragma unroll
    for (int off = 32; off; off >>= 1) v += __shfl_down(v, off, 64);
    const int wid = tid >> 6;
    if ((tid & 63) == 0) red[wid] = v;
    __syncthreads();
    if (tid == 0) {
        float s = 0.f;
#pragma unroll
        for (int i = 0; i < 8; ++i) s += red[i];
        red[8] = s;
    }
    __syncthreads();
    const float s = red[8];
    __syncthreads();
    return s;
}

__global__ __launch_bounds__(512) void head_kernel(const float* __restrict__ h_out,
                                                   const float* __restrict__ fc_w,
                                                   const float* __restrict__ fc_b,
                                                   const float* __restrict__ g1,
                                                   const float* __restrict__ beta1,
                                                   const float* __restrict__ fc1_w,
                                                   const float* __restrict__ fc1_b,
                                                   const float* __restrict__ g2,
                                                   const float* __restrict__ beta2,
                                                   const float* __restrict__ fc2_w,
                                                   const float* __restrict__ fc2_b,
                                                   float* __restrict__ out)
{
    __shared__ float red[9];
    const int tid = threadIdx.x;
    const float inv = 1.f / 512.f;

    float hv[H_];
    const float* hp = h_out + (size_t)tid * H_;
#pragma unroll
    for (int c = 0; c < H_; ++c) hv[c] = hp[c];

    float o[8];
#pragma unroll
    for (int j = 0; j < 8; ++j) {
        float s = fc_b[j];
        for (int c = 0; c < H_; ++c) s += hv[c] * fc_w[j * H_ + c];
        o[j] = s * sigmoidf_(s);
    }
#pragma unroll
    for (int j = 0; j < 8; ++j) {
        const float mu = block_sum(o[j], red, tid) * inv;
        const float m2 = block_sum(o[j] * o[j], red, tid) * inv;
        o[j] = (o[j] - mu) * rsqrtf(m2 - mu * mu + 1e-5f) * g1[j] + beta1[j];
    }
    float p[4];
#pragma unroll
    for (int i = 0; i < 4; ++i) {
        float s = fc1_b[i];
#pragma unroll
        for (int j = 0; j < 8; ++j) s += o[j] * fc1_w[i * 8 + j];
        p[i] = s * sigmoidf_(s);
    }
#pragma unroll
    for (int i = 0; i < 4; ++i) {
        const float mu = block_sum(p[i], red, tid) * inv;
        const float m2 = block_sum(p[i] * p[i], red, tid) * inv;
        p[i] = (p[i] - mu) * rsqrtf(m2 - mu * mu + 1e-5f) * g2[i] + beta2[i];
    }
    float res = fc2_b[0];
#pragma unroll
    for (int i = 0; i < 4; ++i) res += p[i] * fc2_w[i];
    out[tid] = res;
}

// ---------------------------------------------------------------------------
extern "C" void kernel_launch(void* const* d_in, const int* in_sizes, int n_in,
                              void* d_out, int out_size, void* d_ws, size_t ws_size,
                              hipStream_t stream)
{
    const float* x     = (const float*)d_in[0];
    const float* W_ih  = (const float*)d_in[1];
    const float* W_hh  = (const float*)d_in[2];
    const float* b_ih  = (const float*)d_in[3];
    const float* b_hh  = (const float*)d_in[4];

    float* xg    = (float*)d_ws;                        // 512*1024*244*4 = 488 MiB
    float* h_out = xg + (size_t)B_ * T_ * GPX;
    u16*   Whi   = (u16*)(h_out + B_ * H_);
    u16*   Wlo   = Whi + G3 * F_;

    wsplit_kernel<<<dim3((G3 * F_ + 255) / 256), dim3(256), 0, stream>>>(W_ih, Whi, Wlo);
    xg_gemm<<<dim3(512 * 8), dim3(256), 0, stream>>>(x, Whi, Wlo, b_ih, xg);
    gru_kernel<<<dim3(B_ / 2), dim3(512), 0, stream>>>(xg, W_hh, b_hh, h_out);
    head_kernel<<<dim3(1), dim3(512), 0, stream>>>(h_out,
        (const float*)d_in[5], (const float*)d_in[6], (const float*)d_in[7],
        (const float*)d_in[8], (const float*)d_in[9], (const float*)d_in[10],
        (const float*)d_in[11], (const float*)d_in[12], (const float*)d_in[13],
        (const float*)d_in[14], (float*)d_out);
}

// Round 5
// 1542.729 us; speedup vs baseline: 1.1490x; 1.1490x over previous
//
#include <hip/hip_runtime.h>

#define B_  512
#define T_  1024
#define F_  128
#define H_  81
#define G3  243
#define GPX 244                 // xg row stride (floats), layout [b][t][GPX]

typedef unsigned short u16;
typedef __attribute__((ext_vector_type(8))) short bf16x8;
typedef __attribute__((ext_vector_type(4))) float f32x4;
typedef __attribute__((ext_vector_type(2))) float f32x2;

__device__ __forceinline__ float bf2f(u16 u) {
    union { unsigned int i; float f; } v; v.i = ((unsigned int)u) << 16; return v.f;
}
__device__ __forceinline__ u16 f2bf(float f) {
    union { float f; unsigned int i; } v; v.f = f;
    unsigned int i = v.i;
    return (u16)((i + 0x7fffu + ((i >> 16) & 1u)) >> 16);
}
__device__ __forceinline__ float rcp_(float x) { return __builtin_amdgcn_rcpf(x); }
__device__ __forceinline__ float sigmoidf_(float x) { return rcp_(1.f + __expf(-x)); }
__device__ __forceinline__ float tanhf_(float x) {
    return fmaf(-2.f, rcp_(__expf(2.f * x) + 1.f), 1.f);
}
// barrier without vmcnt(0) drain: LDS-correct (lgkmcnt(0) before s_barrier),
// leaves global prefetch loads in flight (m139/AITER technique).
__device__ __forceinline__ void barrier_nodrain() {
    asm volatile("s_waitcnt lgkmcnt(0)\n\ts_barrier" ::: "memory");
}

// ---------------------------------------------------------------------------
// K0: split W_ih fp32 -> bf16 hi/lo.
// ---------------------------------------------------------------------------
__global__ void wsplit_kernel(const float* __restrict__ W,
                              u16* __restrict__ hi, u16* __restrict__ lo)
{
    const int i = blockIdx.x * 256 + threadIdx.x;
    if (i < G3 * F_) {
        const float v = W[i];
        const u16 h = f2bf(v);
        hi[i] = h;
        lo[i] = f2bf(v - bf2f(h));
    }
}

// ---------------------------------------------------------------------------
// K1: xg[b][t][g] = x[b][t]·W_ih[g] + b_ih[g]  (split-bf16 MFMA, 3 terms).
// ---------------------------------------------------------------------------
__global__ __launch_bounds__(256, 2) void xg_gemm(const float* __restrict__ x,
                                                  const u16* __restrict__ Whi,
                                                  const u16* __restrict__ Wlo,
                                                  const float* __restrict__ b_ih,
                                                  float* __restrict__ xg)
{
    __shared__ __align__(16) u16 ws_hi[G3][64];
    __shared__ __align__(16) u16 ws_lo[G3][64];

    const int tid  = threadIdx.x;
    const int wave = tid >> 6, lane = tid & 63;
    const int l15  = lane & 15, q = lane >> 4;
    const int b    = blockIdx.x & 511;
    const int t0   = (blockIdx.x >> 9) << 7;

    f32x4 acc[2][16];
#pragma unroll
    for (int mt = 0; mt < 2; ++mt)
#pragma unroll
        for (int gt = 0; gt < 16; ++gt) acc[mt][gt] = (f32x4){0.f, 0.f, 0.f, 0.f};

    for (int half = 0; half < 2; ++half) {
        if (half) __syncthreads();            // protect LDS reuse
#pragma unroll
        for (int it = 0; it < 16; ++it) {
            const int i = it * 256 + tid;
            if (i < 2 * G3 * 8) {
                const bool lo = (i >= G3 * 8);
                const int j = lo ? (i - G3 * 8) : i;
                const int g = j >> 3, c = j & 7;
                const uint4 v = *(const uint4*)((lo ? Wlo : Whi)
                                                + (size_t)g * F_ + half * 64 + c * 8);
                *(uint4*)&((lo ? ws_lo : ws_hi)[g][((c + g) & 7) * 8]) = v;
            }
        }
        __syncthreads();

#pragma unroll
        for (int kcl = 0; kcl < 2; ++kcl) {
            bf16x8 aHi[2], aLo[2];
#pragma unroll
            for (int mt = 0; mt < 2; ++mt) {
                const float* xr = x + ((size_t)b * T_ + t0 + (wave * 2 + mt) * 16 + l15) * F_
                                  + half * 64 + kcl * 32 + q * 8;
                float xv[8];
                *(float4*)&xv[0] = *(const float4*)(xr);
                *(float4*)&xv[4] = *(const float4*)(xr + 4);
#pragma unroll
                for (int j = 0; j < 8; ++j) {
                    const u16 h = f2bf(xv[j]);
                    aHi[mt][j] = (short)h;
                    aLo[mt][j] = (short)f2bf(xv[j] - bf2f(h));
                }
            }
#pragma unroll
            for (int gt = 0; gt < 16; ++gt) {
                const int gr  = gt * 16 + l15;
                const int grc = (gr < G3) ? gr : (G3 - 1);
                const int sl  = ((kcl * 4 + q + grc) & 7) * 8;
                const bf16x8 bHi = *(const bf16x8*)&ws_hi[grc][sl];
                const bf16x8 bLo = *(const bf16x8*)&ws_lo[grc][sl];
#pragma unroll
                for (int mt = 0; mt < 2; ++mt) {
                    acc[mt][gt] = __builtin_amdgcn_mfma_f32_16x16x32_bf16(aHi[mt], bHi, acc[mt][gt], 0, 0, 0);
                    acc[mt][gt] = __builtin_amdgcn_mfma_f32_16x16x32_bf16(aHi[mt], bLo, acc[mt][gt], 0, 0, 0);
                    acc[mt][gt] = __builtin_amdgcn_mfma_f32_16x16x32_bf16(aLo[mt], bHi, acc[mt][gt], 0, 0, 0);
                }
            }
        }
    }
#pragma unroll
    for (int gt = 0; gt < 16; ++gt) {
        const int g = gt * 16 + l15;
        if (g < G3) {
            const float bias = b_ih[g];
#pragma unroll
            for (int mt = 0; mt < 2; ++mt) {
                const int trow = t0 + (wave * 2 + mt) * 16 + q * 4;
#pragma unroll
                for (int c = 0; c < 4; ++c)
                    xg[((size_t)b * T_ + trow + c) * GPX + g] = acc[mt][gt][c] + bias;
            }
        }
    }
}

// ---------------------------------------------------------------------------
// K2: GRU recurrence, v6 — full-row-triple ownership, ONE barrier per step.
//     Cross-round evidence: VALU busy-time is CONSTANT across v3/v4/v5
//     (265/253/251 us) while dur grew 693->896->1274: every added wave or
//     schedule trick only added STALL (barrier arrival/wake + LDS round-trip
//     latency). So minimize sync structurally instead of hiding it.
//     v6: thread g owns ALL 3 rows of unit g (126 f32x2 = 252 VGPR, pinned).
//     Row sums complete in-thread -> gate computed in-thread: the
//     part-write/barrier/part-read round-trip and the second barrier are
//     GONE. h_s double-buffered: read h_s[cur], write h_s[cur^1], ONE
//     barrier; WAR hazard impossible (all reads of cur precede barrier_t,
//     next-step writes of cur follow it). Block = 128 thr (2 waves, 81
//     active) = one batch; grid 512 = 2 independent blocks/CU (cheapest
//     barrier arrival, decoupled stalls). LDS reads are pure same-address
//     broadcast (21 b128/wave/step): bank-conflict counter should go ~0.
//     Same total FMA; same 42-pair summation shape as the R0 kernel
//     (absmax 4.88e-4 passed). Chain/step ~ 120 (h lat) + 252 (fma issue)
//     + ~85 (reduce+gate) + write + 1 barrier ~= 550-650 cyc vs v3's 812.
// ---------------------------------------------------------------------------
__global__ __launch_bounds__(128, 1) void gru_kernel(const float* __restrict__ xg,
                                                     const float* __restrict__ W_hh,
                                                     const float* __restrict__ b_hh,
                                                     float* __restrict__ h_out)
{
    __shared__ __align__(16) float h_s[2][88];   // double-buffered h, pads 81..87 = 0

    const int tid = threadIdx.x, b = blockIdx.x;
    const bool act = tid < H_;
    const int g = act ? tid : 0;

    // full rows {g, g+81, g+162}, k padded to 84: 3 x 42 f32x2 = 252 VGPRs
    f32x2 w2[3][42];
#pragma unroll
    for (int i = 0; i < 3; ++i) {
        const float* wr = W_hh + (size_t)(g + 81 * i) * H_;
#pragma unroll
        for (int c = 0; c < 42; ++c) {
            const float e0 = (act && 2 * c     < H_) ? wr[2 * c]     : 0.f;
            const float e1 = (act && 2 * c + 1 < H_) ? wr[2 * c + 1] : 0.f;
            w2[i][c] = (f32x2){e0, e1};
        }
    }
#pragma unroll
    for (int i = 0; i < 3; ++i)
#pragma unroll
        for (int c = 0; c < 42; ++c)
            asm volatile("" : "+v"(w2[i][c]));   // pin in ArchVGPRs

    const float br = act ? b_hh[g]          : 0.f;
    const float bz = act ? b_hh[H_ + g]     : 0.f;
    const float bn = act ? b_hh[2 * H_ + g] : 0.f;
    float hreg = 0.f;

    if (tid < 176) ((float*)h_s)[tid] = 0.f;     // zero both buffers + pads
    __syncthreads();

    // per-step x-terms for unit g: xr at +0, xz at +81, xn at +162
    const float* xp = xg + (size_t)b * T_ * GPX + g;
    float xr[4], xz[4], xn[4];
#pragma unroll
    for (int u = 0; u < 4; ++u) {
        xr[u] = xp[(size_t)u * GPX];
        xz[u] = xp[(size_t)u * GPX + 81];
        xn[u] = xp[(size_t)u * GPX + 162];
    }

    int cur = 0;
    for (int t4 = 0; t4 < T_; t4 += 4) {
#pragma unroll
        for (int u = 0; u < 4; ++u) {
            const int t = t4 + u;
            // --- 3 full-row dots: 126 pk_fma, 6 independent chains ---
            f32x2 a0A = {0.f, 0.f}, a0B = {0.f, 0.f};
            f32x2 a1A = {0.f, 0.f}, a1B = {0.f, 0.f};
            f32x2 a2A = {0.f, 0.f}, a2B = {0.f, 0.f};
            const float4* hb = (const float4*)h_s[cur & 1];
#pragma unroll
            for (int c = 0; c < 21; ++c) {
                const float4 h4 = hb[c];               // same-addr broadcast
                const f32x2 lo = {h4.x, h4.y}, hi = {h4.z, h4.w};
                a0A = __builtin_elementwise_fma(w2[0][2 * c],     lo, a0A);
                a0B = __builtin_elementwise_fma(w2[0][2 * c + 1], hi, a0B);
                a1A = __builtin_elementwise_fma(w2[1][2 * c],     lo, a1A);
                a1B = __builtin_elementwise_fma(w2[1][2 * c + 1], hi, a1B);
                a2A = __builtin_elementwise_fma(w2[2][2 * c],     lo, a2A);
                a2B = __builtin_elementwise_fma(w2[2][2 * c + 1], hi, a2B);
            }
            const f32x2 t0 = a0A + a0B, t1 = a1A + a1B, t2 = a2A + a2B;
            const float hr = t0.x + t0.y + br;
            const float hz = t1.x + t1.y + bz;
            const float hn = t2.x + t2.y + bn;
            // --- gate, fully in-thread ---
            const float rr = sigmoidf_(xr[u] + hr);
            const float zz = sigmoidf_(xz[u] + hz);
            const float nn = tanhf_(fmaf(rr, hn, xn[u]));
            hreg = nn + zz * (hreg - nn);
            if (act) h_s[(cur & 1) ^ 1][g] = hreg;
            barrier_nodrain();                       // the ONLY sync per step
            cur ^= 1;
            // refill prefetch slot u with step t+4 (stays in flight)
            const int tn = (t + 4 < T_) ? (t + 4) : (T_ - 1);
            xr[u] = xp[(size_t)tn * GPX];
            xz[u] = xp[(size_t)tn * GPX + 81];
            xn[u] = xp[(size_t)tn * GPX + 162];
        }
    }

    if (act) h_out[(size_t)b * H_ + g] = hreg;
}

// ---------------------------------------------------------------------------
// K3: head. One block, 512 threads (thread = batch row), fp32 throughout.
// ---------------------------------------------------------------------------
__device__ __forceinline__ float block_sum(float v, float* red, int tid) {
#pragma unroll
    for (int off = 32; off; off >>= 1) v += __shfl_down(v, off, 64);
    const int wid = tid >> 6;
    if ((tid & 63) == 0) red[wid] = v;
    __syncthreads();
    if (tid == 0) {
        float s = 0.f;
#pragma unroll
        for (int i = 0; i < 8; ++i) s += red[i];
        red[8] = s;
    }
    __syncthreads();
    const float s = red[8];
    __syncthreads();
    return s;
}

__global__ __launch_bounds__(512) void head_kernel(const float* __restrict__ h_out,
                                                   const float* __restrict__ fc_w,
                                                   const float* __restrict__ fc_b,
                                                   const float* __restrict__ g1,
                                                   const float* __restrict__ beta1,
                                                   const float* __restrict__ fc1_w,
                                                   const float* __restrict__ fc1_b,
                                                   const float* __restrict__ g2,
                                                   const float* __restrict__ beta2,
                                                   const float* __restrict__ fc2_w,
                                                   const float* __restrict__ fc2_b,
                                                   float* __restrict__ out)
{
    __shared__ float red[9];
    const int tid = threadIdx.x;
    const float inv = 1.f / 512.f;

    float hv[H_];
    const float* hp = h_out + (size_t)tid * H_;
#pragma unroll
    for (int c = 0; c < H_; ++c) hv[c] = hp[c];

    float o[8];
#pragma unroll
    for (int j = 0; j < 8; ++j) {
        float s = fc_b[j];
        for (int c = 0; c < H_; ++c) s += hv[c] * fc_w[j * H_ + c];
        o[j] = s * sigmoidf_(s);
    }
#pragma unroll
    for (int j = 0; j < 8; ++j) {
        const float mu = block_sum(o[j], red, tid) * inv;
        const float m2 = block_sum(o[j] * o[j], red, tid) * inv;
        o[j] = (o[j] - mu) * rsqrtf(m2 - mu * mu + 1e-5f) * g1[j] + beta1[j];
    }
    float p[4];
#pragma unroll
    for (int i = 0; i < 4; ++i) {
        float s = fc1_b[i];
#pragma unroll
        for (int j = 0; j < 8; ++j) s += o[j] * fc1_w[i * 8 + j];
        p[i] = s * sigmoidf_(s);
    }
#pragma unroll
    for (int i = 0; i < 4; ++i) {
        const float mu = block_sum(p[i], red, tid) * inv;
        const float m2 = block_sum(p[i] * p[i], red, tid) * inv;
        p[i] = (p[i] - mu) * rsqrtf(m2 - mu * mu + 1e-5f) * g2[i] + beta2[i];
    }
    float res = fc2_b[0];
#pragma unroll
    for (int i = 0; i < 4; ++i) res += p[i] * fc2_w[i];
    out[tid] = res;
}

// ---------------------------------------------------------------------------
extern "C" void kernel_launch(void* const* d_in, const int* in_sizes, int n_in,
                              void* d_out, int out_size, void* d_ws, size_t ws_size,
                              hipStream_t stream)
{
    const float* x     = (const float*)d_in[0];
    const float* W_ih  = (const float*)d_in[1];
    const float* W_hh  = (const float*)d_in[2];
    const float* b_ih  = (const float*)d_in[3];
    const float* b_hh  = (const float*)d_in[4];

    float* xg    = (float*)d_ws;                        // 512*1024*244*4 = 488 MiB
    float* h_out = xg + (size_t)B_ * T_ * GPX;
    u16*   Whi   = (u16*)(h_out + B_ * H_);
    u16*   Wlo   = Whi + G3 * F_;

    wsplit_kernel<<<dim3((G3 * F_ + 255) / 256), dim3(256), 0, stream>>>(W_ih, Whi, Wlo);
    xg_gemm<<<dim3(512 * 8), dim3(256), 0, stream>>>(x, Whi, Wlo, b_ih, xg);
    gru_kernel<<<dim3(B_), dim3(128), 0, stream>>>(xg, W_hh, b_hh, h_out);
    head_kernel<<<dim3(1), dim3(512), 0, stream>>>(h_out,
        (const float*)d_in[5], (const float*)d_in[6], (const float*)d_in[7],
        (const float*)d_in[8], (const float*)d_in[9], (const float*)d_in[10],
        (const float*)d_in[11], (const float*)d_in[12], (const float*)d_in[13],
        (const float*)d_in[14], (float*)d_out);
}

// Round 7
// 1177.794 us; speedup vs baseline: 1.5050x; 1.3098x over previous
//
#include <hip/hip_runtime.h>

#define B_  512
#define T_  1024
#define F_  128
#define H_  81
#define G3  243
#define GPX 244                 // xg row stride (floats), layout [b][t][GPX]

typedef unsigned short u16;
typedef __attribute__((ext_vector_type(8))) short bf16x8;
typedef __attribute__((ext_vector_type(4))) float f32x4;
typedef __attribute__((ext_vector_type(2))) float f32x2;

__device__ __forceinline__ float bf2f(u16 u) {
    union { unsigned int i; float f; } v; v.i = ((unsigned int)u) << 16; return v.f;
}
__device__ __forceinline__ u16 f2bf(float f) {
    union { float f; unsigned int i; } v; v.f = f;
    unsigned int i = v.i;
    return (u16)((i + 0x7fffu + ((i >> 16) & 1u)) >> 16);
}
__device__ __forceinline__ float rcp_(float x) { return __builtin_amdgcn_rcpf(x); }
__device__ __forceinline__ float sigmoidf_(float x) { return rcp_(1.f + __expf(-x)); }
__device__ __forceinline__ float tanhf_(float x) {
    return fmaf(-2.f, rcp_(__expf(2.f * x) + 1.f), 1.f);
}
// barrier without vmcnt(0) drain: LDS-correct (lgkmcnt(0) before s_barrier),
// leaves global prefetch loads in flight (m139/AITER technique).
__device__ __forceinline__ void barrier_nodrain() {
    asm volatile("s_waitcnt lgkmcnt(0)\n\ts_barrier" ::: "memory");
}

// ---------------------------------------------------------------------------
// K0: split W_ih fp32 -> bf16 hi/lo.
// ---------------------------------------------------------------------------
__global__ void wsplit_kernel(const float* __restrict__ W,
                              u16* __restrict__ hi, u16* __restrict__ lo)
{
    const int i = blockIdx.x * 256 + threadIdx.x;
    if (i < G3 * F_) {
        const float v = W[i];
        const u16 h = f2bf(v);
        hi[i] = h;
        lo[i] = f2bf(v - bf2f(h));
    }
}

// ---------------------------------------------------------------------------
// K1: xg[b][t][g] = x[b][t]·W_ih[g] + b_ih[g]  (split-bf16 MFMA, 3 terms).
// ---------------------------------------------------------------------------
__global__ __launch_bounds__(256, 2) void xg_gemm(const float* __restrict__ x,
                                                  const u16* __restrict__ Whi,
                                                  const u16* __restrict__ Wlo,
                                                  const float* __restrict__ b_ih,
                                                  float* __restrict__ xg)
{
    __shared__ __align__(16) u16 ws_hi[G3][64];
    __shared__ __align__(16) u16 ws_lo[G3][64];

    const int tid  = threadIdx.x;
    const int wave = tid >> 6, lane = tid & 63;
    const int l15  = lane & 15, q = lane >> 4;
    const int b    = blockIdx.x & 511;
    const int t0   = (blockIdx.x >> 9) << 7;

    f32x4 acc[2][16];
#pragma unroll
    for (int mt = 0; mt < 2; ++mt)
#pragma unroll
        for (int gt = 0; gt < 16; ++gt) acc[mt][gt] = (f32x4){0.f, 0.f, 0.f, 0.f};

    for (int half = 0; half < 2; ++half) {
        if (half) __syncthreads();            // protect LDS reuse
#pragma unroll
        for (int it = 0; it < 16; ++it) {
            const int i = it * 256 + tid;
            if (i < 2 * G3 * 8) {
                const bool lo = (i >= G3 * 8);
                const int j = lo ? (i - G3 * 8) : i;
                const int g = j >> 3, c = j & 7;
                const uint4 v = *(const uint4*)((lo ? Wlo : Whi)
                                                + (size_t)g * F_ + half * 64 + c * 8);
                *(uint4*)&((lo ? ws_lo : ws_hi)[g][((c + g) & 7) * 8]) = v;
            }
        }
        __syncthreads();

#pragma unroll
        for (int kcl = 0; kcl < 2; ++kcl) {
            bf16x8 aHi[2], aLo[2];
#pragma unroll
            for (int mt = 0; mt < 2; ++mt) {
                const float* xr = x + ((size_t)b * T_ + t0 + (wave * 2 + mt) * 16 + l15) * F_
                                  + half * 64 + kcl * 32 + q * 8;
                float xv[8];
                *(float4*)&xv[0] = *(const float4*)(xr);
                *(float4*)&xv[4] = *(const float4*)(xr + 4);
#pragma unroll
                for (int j = 0; j < 8; ++j) {
                    const u16 h = f2bf(xv[j]);
                    aHi[mt][j] = (short)h;
                    aLo[mt][j] = (short)f2bf(xv[j] - bf2f(h));
                }
            }
#pragma unroll
            for (int gt = 0; gt < 16; ++gt) {
                const int gr  = gt * 16 + l15;
                const int grc = (gr < G3) ? gr : (G3 - 1);
                const int sl  = ((kcl * 4 + q + grc) & 7) * 8;
                const bf16x8 bHi = *(const bf16x8*)&ws_hi[grc][sl];
                const bf16x8 bLo = *(const bf16x8*)&ws_lo[grc][sl];
#pragma unroll
                for (int mt = 0; mt < 2; ++mt) {
                    acc[mt][gt] = __builtin_amdgcn_mfma_f32_16x16x32_bf16(aHi[mt], bHi, acc[mt][gt], 0, 0, 0);
                    acc[mt][gt] = __builtin_amdgcn_mfma_f32_16x16x32_bf16(aHi[mt], bLo, acc[mt][gt], 0, 0, 0);
                    acc[mt][gt] = __builtin_amdgcn_mfma_f32_16x16x32_bf16(aLo[mt], bHi, acc[mt][gt], 0, 0, 0);
                }
            }
        }
    }
#pragma unroll
    for (int gt = 0; gt < 16; ++gt) {
        const int g = gt * 16 + l15;
        if (g < G3) {
            const float bias = b_ih[g];
#pragma unroll
            for (int mt = 0; mt < 2; ++mt) {
                const int trow = t0 + (wave * 2 + mt) * 16 + q * 4;
#pragma unroll
                for (int c = 0; c < 4; ++c)
                    xg[((size_t)b * T_ + trow + c) * GPX + g] = acc[mt][gt][c] + bias;
            }
        }
    }
}

// ---------------------------------------------------------------------------
// K2: GRU recurrence, v7 — EXACT v3 structure (the only one that measured
//     693 us; v4/v5/v6 all regressed) + float4-packed part round-trip.
//     Cost model fitting all rounds: phases are barrier-serialized; within a
//     phase, waves serialize on the shared LDS pipe (~12cyc/b128, ~6/b32 per
//     CU, broadcasts included). v3 ledger/combined-step: h-broadcast 56 b128
//     (fixed floor) + part writes ~28 b32-ops + gate reads ~40 b32-ops.
//     v7 packs the part round-trip: dot thread writes ONE float4
//     {s0,s1,s2,xv} per batch (lane-consecutive b128 = linear 1KB/wave,
//     conflict-free) replacing 3 scattered b32 + xn b32; gate reads 3 b128
//     replacing 10 b32. Write ops 28->8, gate-read ops 40->12. Gate sum
//     order unchanged (p0+p1+p2+bias) -> bitwise-identical result.
//     VGPR lesson (R0/v2/v6): 84 f32x2 weight-pairs/thread is the proven
//     residency ceiling — keep 3x14 per thread, asm-pinned.
// ---------------------------------------------------------------------------
__global__ __launch_bounds__(256, 1) void gru_kernel(const float* __restrict__ xg,
                                                     const float* __restrict__ W_hh,
                                                     const float* __restrict__ b_hh,
                                                     float* __restrict__ h_out)
{
    __shared__ __align__(16) float h_s[2][88];       // h padded, 81..87 = 0
    __shared__ __align__(16) float4 part4[2][3][84]; // [batch][p][j] = {s0,s1,s2,xv}

    const int tid = threadIdx.x;
    const int b0 = blockIdx.x * 2, b1 = b0 + 1;
    const bool act = tid < G3;
    const int p   = (tid >= 162) ? 2 : ((tid >= 81) ? 1 : 0);
    const int j   = act ? (tid - p * 81) : 0;        // hidden-unit index
    const int k0  = p * 28;                          // k-third base (padded H=84)

    // weights: rows {j, j+81, j+162}, k in [k0, k0+28); zero-padded past H
    f32x2 w2[3][14];
#pragma unroll
    for (int i = 0; i < 3; ++i) {
        const float* wr = W_hh + (size_t)(j + 81 * i) * H_ + k0;
#pragma unroll
        for (int c = 0; c < 14; ++c) {
            const float e0 = (act && (k0 + 2 * c)     < H_) ? wr[2 * c]     : 0.f;
            const float e1 = (act && (k0 + 2 * c + 1) < H_) ? wr[2 * c + 1] : 0.f;
            w2[i][c] = (f32x2){e0, e1};
        }
    }
#pragma unroll
    for (int i = 0; i < 3; ++i)
#pragma unroll
        for (int c = 0; c < 14; ++c)
            asm volatile("" : "+v"(w2[i][c]));       // pin in ArchVGPRs

    // gate roles: gq=0 -> batch0 (tid 0..80), gq=1 -> batch1 (tid 128..208)
    const int gq = (tid < H_) ? 0 : ((tid >= 128 && tid < 128 + H_) ? 1 : -1);
    const int gi = (gq == 1) ? (tid - 128) : tid;
    const float br = (gq >= 0) ? b_hh[gi]          : 0.f;
    const float bz = (gq >= 0) ? b_hh[H_ + gi]     : 0.f;
    const float bn = (gq >= 0) ? b_hh[2 * H_ + gi] : 0.f;
    float hreg = 0.f;

    if (tid < 176) ((float*)h_s)[tid] = 0.f;
    __syncthreads();

    const float* xp0 = xg + (size_t)b0 * T_ * GPX + (act ? tid : 0);
    const float* xp1 = xg + (size_t)b1 * T_ * GPX + (act ? tid : 0);
    float xf0[4], xf1[4];
#pragma unroll
    for (int u = 0; u < 4; ++u) {
        xf0[u] = xp0[(size_t)u * GPX];
        xf1[u] = xp1[(size_t)u * GPX];
    }

    for (int t4 = 0; t4 < T_; t4 += 4) {
#pragma unroll
        for (int u = 0; u < 4; ++u) {
            const float xv0 = xf0[u], xv1 = xf1[u];
            // --- dot: 3 rows x 28 k x 2 batches, shared weights ---
            f32x2 aA0[3], aB0[3], aA1[3], aB1[3];
#pragma unroll
            for (int i = 0; i < 3; ++i) {
                aA0[i] = (f32x2){0.f, 0.f}; aB0[i] = (f32x2){0.f, 0.f};
                aA1[i] = (f32x2){0.f, 0.f}; aB1[i] = (f32x2){0.f, 0.f};
            }
#pragma unroll
            for (int c = 0; c < 7; ++c) {
                const float4 h40 = ((const float4*)h_s[0])[p * 7 + c];
                const float4 h41 = ((const float4*)h_s[1])[p * 7 + c];
                const f32x2 lo0 = {h40.x, h40.y}, hi0 = {h40.z, h40.w};
                const f32x2 lo1 = {h41.x, h41.y}, hi1 = {h41.z, h41.w};
#pragma unroll
                for (int i = 0; i < 3; ++i) {
                    aA0[i] = __builtin_elementwise_fma(w2[i][2 * c],     lo0, aA0[i]);
                    aB0[i] = __builtin_elementwise_fma(w2[i][2 * c + 1], hi0, aB0[i]);
                    aA1[i] = __builtin_elementwise_fma(w2[i][2 * c],     lo1, aA1[i]);
                    aB1[i] = __builtin_elementwise_fma(w2[i][2 * c + 1], hi1, aB1[i]);
                }
            }
            const f32x2 t00 = aA0[0] + aB0[0], t01 = aA0[1] + aB0[1], t02 = aA0[2] + aB0[2];
            const f32x2 t10 = aA1[0] + aB1[0], t11 = aA1[1] + aB1[1], t12 = aA1[2] + aB1[2];
            float s00 = t00.x + t00.y, s01 = t01.x + t01.y, s02 = t02.x + t02.y;
            float s10 = t10.x + t10.y, s11 = t11.x + t11.y, s12 = t12.x + t12.y;
            // fold this thread's own x-term into its own row's partial
            s00 += (p == 0) ? xv0 : 0.f;
            s01 += (p == 1) ? xv0 : 0.f;
            s10 += (p == 0) ? xv1 : 0.f;
            s11 += (p == 1) ? xv1 : 0.f;
            if (act) {
                // packed part write: one b128 per batch (lane-linear, conflict-free)
                part4[0][p][j] = (float4){s00, s01, s02, xv0};
                part4[1][p][j] = (float4){s10, s11, s12, xv1};
            }
            barrier_nodrain();
            // --- gates: b0 on waves 0/1, b1 on waves 2/3 ---
            if (gq >= 0) {
                const float4 q0 = part4[gq][0][gi];
                const float4 q1 = part4[gq][1][gi];
                const float4 q2 = part4[gq][2][gi];
                const float prer = q0.x + q1.x + q2.x + br;
                const float prez = q0.y + q1.y + q2.y + bz;
                const float hn   = q0.z + q1.z + q2.z + bn;
                const float rr = sigmoidf_(prer);
                const float zz = sigmoidf_(prez);
                const float nn = tanhf_(fmaf(rr, hn, q2.w));
                hreg = nn + zz * (hreg - nn);
                h_s[gq][gi] = hreg;
            }
            barrier_nodrain();
            // prefetch 4 steps ahead (clamped; stays in flight across fences)
            const int tn = (t4 + u + 4 < T_) ? (t4 + u + 4) : (T_ - 1);
            xf0[u] = xp0[(size_t)tn * GPX];
            xf1[u] = xp1[(size_t)tn * GPX];
        }
    }

    if (gq == 0)      h_out[(size_t)b0 * H_ + gi] = hreg;
    else if (gq == 1) h_out[(size_t)b1 * H_ + gi] = hreg;
}

// ---------------------------------------------------------------------------
// K3: head. One block, 512 threads (thread = batch row), fp32 throughout.
// ---------------------------------------------------------------------------
__device__ __forceinline__ float block_sum(float v, float* red, int tid) {
#pragma unroll
    for (int off = 32; off; off >>= 1) v += __shfl_down(v, off, 64);
    const int wid = tid >> 6;
    if ((tid & 63) == 0) red[wid] = v;
    __syncthreads();
    if (tid == 0) {
        float s = 0.f;
#pragma unroll
        for (int i = 0; i < 8; ++i) s += red[i];
        red[8] = s;
    }
    __syncthreads();
    const float s = red[8];
    __syncthreads();
    return s;
}

__global__ __launch_bounds__(512) void head_kernel(const float* __restrict__ h_out,
                                                   const float* __restrict__ fc_w,
                                                   const float* __restrict__ fc_b,
                                                   const float* __restrict__ g1,
                                                   const float* __restrict__ beta1,
                                                   const float* __restrict__ fc1_w,
                                                   const float* __restrict__ fc1_b,
                                                   const float* __restrict__ g2,
                                                   const float* __restrict__ beta2,
                                                   const float* __restrict__ fc2_w,
                                                   const float* __restrict__ fc2_b,
                                                   float* __restrict__ out)
{
    __shared__ float red[9];
    const int tid = threadIdx.x;
    const float inv = 1.f / 512.f;

    float hv[H_];
    const float* hp = h_out + (size_t)tid * H_;
#pragma unroll
    for (int c = 0; c < H_; ++c) hv[c] = hp[c];

    float o[8];
#pragma unroll
    for (int j = 0; j < 8; ++j) {
        float s = fc_b[j];
        for (int c = 0; c < H_; ++c) s += hv[c] * fc_w[j * H_ + c];
        o[j] = s * sigmoidf_(s);
    }
#pragma unroll
    for (int j = 0; j < 8; ++j) {
        const float mu = block_sum(o[j], red, tid) * inv;
        const float m2 = block_sum(o[j] * o[j], red, tid) * inv;
        o[j] = (o[j] - mu) * rsqrtf(m2 - mu * mu + 1e-5f) * g1[j] + beta1[j];
    }
    float p[4];
#pragma unroll
    for (int i = 0; i < 4; ++i) {
        float s = fc1_b[i];
#pragma unroll
        for (int j = 0; j < 8; ++j) s += o[j] * fc1_w[i * 8 + j];
        p[i] = s * sigmoidf_(s);
    }
#pragma unroll
    for (int i = 0; i < 4; ++i) {
        const float mu = block_sum(p[i], red, tid) * inv;
        const float m2 = block_sum(p[i] * p[i], red, tid) * inv;
        p[i] = (p[i] - mu) * rsqrtf(m2 - mu * mu + 1e-5f) * g2[i] + beta2[i];
    }
    float res = fc2_b[0];
#pragma unroll
    for (int i = 0; i < 4; ++i) res += p[i] * fc2_w[i];
    out[tid] = res;
}

// ---------------------------------------------------------------------------
extern "C" void kernel_launch(void* const* d_in, const int* in_sizes, int n_in,
                              void* d_out, int out_size, void* d_ws, size_t ws_size,
                              hipStream_t stream)
{
    const float* x     = (const float*)d_in[0];
    const float* W_ih  = (const float*)d_in[1];
    const float* W_hh  = (const float*)d_in[2];
    const float* b_ih  = (const float*)d_in[3];
    const float* b_hh  = (const float*)d_in[4];

    float* xg    = (float*)d_ws;                        // 512*1024*244*4 = 488 MiB
    float* h_out = xg + (size_t)B_ * T_ * GPX;
    u16*   Whi   = (u16*)(h_out + B_ * H_);
    u16*   Wlo   = Whi + G3 * F_;

    wsplit_kernel<<<dim3((G3 * F_ + 255) / 256), dim3(256), 0, stream>>>(W_ih, Whi, Wlo);
    xg_gemm<<<dim3(512 * 8), dim3(256), 0, stream>>>(x, Whi, Wlo, b_ih, xg);
    gru_kernel<<<dim3(B_ / 2), dim3(256), 0, stream>>>(xg, W_hh, b_hh, h_out);
    head_kernel<<<dim3(1), dim3(512), 0, stream>>>(h_out,
        (const float*)d_in[5], (const float*)d_in[6], (const float*)d_in[7],
        (const float*)d_in[8], (const float*)d_in[9], (const float*)d_in[10],
        (const float*)d_in[11], (const float*)d_in[12], (const float*)d_in[13],
        (const float*)d_in[14], (float*)d_out);
}